// Round 1
// baseline (711.213 us; speedup 1.0000x reference)
//
#include <hip/hip_runtime.h>
#include <hip/hip_bf16.h>
#include <stdint.h>

#define B_ 64
#define S_ 1024
#define F_ 1024
#define U_ 1024
#define M_ (B_*S_)

typedef __attribute__((ext_vector_type(4))) float  f4;
typedef __attribute__((ext_vector_type(4))) float  f32x4;
typedef __attribute__((ext_vector_type(8))) short  short8;
typedef unsigned int u32;

static __device__ __forceinline__ short f2bf(float x){
    union { float f; uint32_t u; } v; v.f = x;
    uint32_t u = v.u;
    u += 0x7fffu + ((u >> 16) & 1u);   // round-to-nearest-even
    return (short)(u >> 16);
}

static __device__ __forceinline__ void glds16(const void* g, void* l){
    __builtin_amdgcn_global_load_lds(
        (const __attribute__((address_space(1))) u32*)g,
        (__attribute__((address_space(3))) u32*)l, 16, 0, 0);
}

static __device__ __forceinline__ float fast_tanh(float x){
    float e = __expf(2.f * x);
    return 1.f - 2.f / (e + 1.f);
}

// ---------------------------------------------------------------------------
// Pack W1 [F,U] fp32 -> bf16 tiles in the exact LDS image the GEMM wants:
// tile (kb, nb) = 8KB at offset (kb*8+nb)*8192; inside: [kgrp 0..3][n 0..127][8 k]
// ---------------------------------------------------------------------------
__global__ void pack_w1(const float* __restrict__ W1, short* __restrict__ Bws){
    int g = blockIdx.x * 256 + threadIdx.x;      // 131072 groups of 8 bf16
    int n    =  g        & 127;
    int kgrp = (g >> 7)  & 3;
    int nb   = (g >> 9)  & 7;
    int kb   =  g >> 12;
    int u  = nb*128 + n;
    int f0 = kb*32 + kgrp*8;
    short8 o;
#pragma unroll
    for (int j = 0; j < 8; ++j)
        o[j] = f2bf(W1[(size_t)(f0 + j)*U_ + u]);
    *(short8*)&Bws[(size_t)g * 8] = o;
}

// ---------------------------------------------------------------------------
// hb[b][u] = hidden[b] @ W2[:,u] + W2_b[u] + W1_b[u]   (exact fp32)
// ---------------------------------------------------------------------------
__global__ void hb_kernel(const float* __restrict__ hidden, const float* __restrict__ W2,
                          const float* __restrict__ W2b, const float* __restrict__ W1b,
                          float* __restrict__ hb){
    __shared__ float hs[U_];
    int b = blockIdx.y, t = threadIdx.x;
    for (int i = t; i < U_; i += 256) hs[i] = hidden[b*U_ + i];
    __syncthreads();
    int u = blockIdx.x*256 + t;
    float acc = W1b[u] + W2b[u];
#pragma unroll 8
    for (int k = 0; k < U_; ++k)
        acc = fmaf(hs[k], W2[(size_t)k*U_ + u], acc);
    hb[b*U_ + u] = acc;
}

// ---------------------------------------------------------------------------
// Fused GEMM + tanh + V-dot:  logits[m] += sum_u V[u]*tanh(feat@W1 + hb)
// 128x128 tile, BK=32, 4 waves (2x2), 16x16x32 bf16 MFMA, 4x4 frags/wave.
// A: fp32 global -> regs -> cvt bf16 -> LDS [kgrp][m][8]
// B: pre-packed bf16 ws tiles -> global_load_lds (double buffered)
// ---------------------------------------------------------------------------
__global__ __launch_bounds__(256) void gemm_score(
        const float* __restrict__ A, const short* __restrict__ Bws,
        const float* __restrict__ hb, const float* __restrict__ Vw,
        float* __restrict__ logits){
    __shared__ short Abuf[4096];       // 8 KB  [kgrp4][m128][8]
    __shared__ short Bbuf[2][4096];    // 2x8KB [kgrp4][n128][8]

    const int t   = threadIdx.x;
    const int bid = blockIdx.x;
    const int mb = bid >> 3, nb = bid & 7;
    const int m0 = mb*128,  n0 = nb*128;
    const int batch = m0 >> 10;                 // 128-row blocks never straddle b
    const int w = t >> 6, l = t & 63;
    const int wr = w >> 1, wc = w & 1;
    const int kg = l >> 4, fr = l & 15;
    const int ar = t >> 1, ah = t & 1;          // A staging: row, k-half

    const float* aptr = A + (size_t)(m0 + ar)*F_ + ah*16;

    f32x4 acc[4][4];
#pragma unroll
    for (int i = 0; i < 4; ++i)
#pragma unroll
        for (int j = 0; j < 4; ++j) acc[i][j] = (f32x4)0.f;

    // ---- prologue: A regs for kt=0, B glds for kt=0 into buf 0
    f4 a0 = *(const f4*)(aptr + 0);
    f4 a1 = *(const f4*)(aptr + 4);
    f4 a2 = *(const f4*)(aptr + 8);
    f4 a3 = *(const f4*)(aptr + 12);
    {
        const char* src = (const char*)Bws + ((size_t)(0*8 + nb) << 13) + (w<<11) + (l<<4);
        char* dst = (char*)&Bbuf[0][0] + (w<<11);
        glds16(src, dst);
        glds16(src + 1024, dst + 1024);
    }

    for (int kt = 0; kt < 32; ++kt){
        const int sel = kt & 1;
        // convert + write A tile
        short8 s0, s1;
        s0[0]=f2bf(a0[0]); s0[1]=f2bf(a0[1]); s0[2]=f2bf(a0[2]); s0[3]=f2bf(a0[3]);
        s0[4]=f2bf(a1[0]); s0[5]=f2bf(a1[1]); s0[6]=f2bf(a1[2]); s0[7]=f2bf(a1[3]);
        s1[0]=f2bf(a2[0]); s1[1]=f2bf(a2[1]); s1[2]=f2bf(a2[2]); s1[3]=f2bf(a2[3]);
        s1[4]=f2bf(a3[0]); s1[5]=f2bf(a3[1]); s1[6]=f2bf(a3[2]); s1[7]=f2bf(a3[3]);
        *(short8*)&Abuf[((2*ah+0)*128 + ar)*8] = s0;
        *(short8*)&Abuf[((2*ah+1)*128 + ar)*8] = s1;
        __syncthreads();                        // A visible + B(kt) glds drained

        if (kt < 31){                           // prefetch next tile (overlaps MFMA)
            const float* ap = aptr + (kt+1)*32;
            a0 = *(const f4*)(ap + 0);
            a1 = *(const f4*)(ap + 4);
            a2 = *(const f4*)(ap + 8);
            a3 = *(const f4*)(ap + 12);
            const char* src = (const char*)Bws + ((size_t)((kt+1)*8 + nb) << 13) + (w<<11) + (l<<4);
            char* dst = (char*)&Bbuf[sel^1][0] + (w<<11);
            glds16(src, dst);
            glds16(src + 1024, dst + 1024);
        }

        short8 af[4], bfr[4];
#pragma unroll
        for (int i = 0; i < 4; ++i)
            af[i] = *(const short8*)&Abuf[(kg*128 + wr*64 + i*16 + fr)*8];
#pragma unroll
        for (int j = 0; j < 4; ++j)
            bfr[j] = *(const short8*)&Bbuf[sel][(kg*128 + wc*64 + j*16 + fr)*8];
#pragma unroll
        for (int i = 0; i < 4; ++i)
#pragma unroll
            for (int j = 0; j < 4; ++j)
                acc[i][j] = __builtin_amdgcn_mfma_f32_16x16x32_bf16(af[i], bfr[j], acc[i][j], 0, 0, 0);
        __syncthreads();                        // protect Abuf before next overwrite
    }

    // ---- epilogue: tanh + V-dot, reduce 16 lanes -> row partial, atomicAdd
    float hv[4], vv[4];
#pragma unroll
    for (int j = 0; j < 4; ++j){
        int u = n0 + wc*64 + j*16 + fr;
        hv[j] = hb[batch*U_ + u];
        vv[j] = Vw[u];
    }
#pragma unroll
    for (int i = 0; i < 4; ++i){
#pragma unroll
        for (int reg = 0; reg < 4; ++reg){
            float sum = 0.f;
#pragma unroll
            for (int j = 0; j < 4; ++j){
                float sc = fast_tanh(acc[i][j][reg] + hv[j]);
                sum = fmaf(vv[j], sc, sum);
            }
            sum += __shfl_xor(sum, 1, 64);
            sum += __shfl_xor(sum, 2, 64);
            sum += __shfl_xor(sum, 4, 64);
            sum += __shfl_xor(sum, 8, 64);
            if (fr == 0)
                atomicAdd(&logits[m0 + wr*64 + i*16 + kg*4 + reg], sum);
        }
    }
}

// ---------------------------------------------------------------------------
// softmax over S per batch, in place (logits -> attention weights)
// ---------------------------------------------------------------------------
__global__ void softmax_seq(float* __restrict__ lg){
    __shared__ float red[4], red2[4];
    int b = blockIdx.x, t = threadIdx.x;
    float v[4];
#pragma unroll
    for (int c = 0; c < 4; ++c) v[c] = lg[b*1024 + c*256 + t];
    float mx = fmaxf(fmaxf(v[0], v[1]), fmaxf(v[2], v[3]));
#pragma unroll
    for (int off = 32; off >= 1; off >>= 1) mx = fmaxf(mx, __shfl_xor(mx, off, 64));
    if ((t & 63) == 0) red[t >> 6] = mx;
    __syncthreads();
    mx = fmaxf(fmaxf(red[0], red[1]), fmaxf(red[2], red[3]));
    float e[4], s = 0.f;
#pragma unroll
    for (int c = 0; c < 4; ++c){ e[c] = __expf(v[c] - mx); s += e[c]; }
#pragma unroll
    for (int off = 32; off >= 1; off >>= 1) s += __shfl_xor(s, off, 64);
    if ((t & 63) == 0) red2[t >> 6] = s;
    __syncthreads();
    s = red2[0] + red2[1] + red2[2] + red2[3];
    float inv = 1.f / s;
#pragma unroll
    for (int c = 0; c < 4; ++c) lg[b*1024 + c*256 + t] = e[c] * inv;
}

// ---------------------------------------------------------------------------
// context[b][f] = sum_s w[b,s] * features[b,s,f]
// ---------------------------------------------------------------------------
__global__ void context_kernel(const float* __restrict__ feats, const float* __restrict__ wts,
                               float* __restrict__ ctx){
    __shared__ float wsh[256];
    int fb = blockIdx.x, sh = blockIdx.y, b = blockIdx.z;
    int t = threadIdx.x;
    wsh[t] = wts[b*1024 + sh*256 + t];
    __syncthreads();
    int f = fb*256 + t;
    const float* fp = feats + ((size_t)b*1024 + sh*256)*1024 + f;
    float a0 = 0.f, a1 = 0.f, a2 = 0.f, a3 = 0.f;
    for (int s = 0; s < 256; s += 4){
        a0 = fmaf(wsh[s+0], fp[(size_t)(s+0)*1024], a0);
        a1 = fmaf(wsh[s+1], fp[(size_t)(s+1)*1024], a1);
        a2 = fmaf(wsh[s+2], fp[(size_t)(s+2)*1024], a2);
        a3 = fmaf(wsh[s+3], fp[(size_t)(s+3)*1024], a3);
    }
    atomicAdd(&ctx[b*1024 + f], a0 + a1 + a2 + a3);
}

// ---------------------------------------------------------------------------
extern "C" void kernel_launch(void* const* d_in, const int* in_sizes, int n_in,
                              void* d_out, int out_size, void* d_ws, size_t ws_size,
                              hipStream_t stream){
    const float* features = (const float*)d_in[0];
    const float* hidden   = (const float*)d_in[1];
    const float* W1w      = (const float*)d_in[2];
    const float* W1b      = (const float*)d_in[3];
    const float* W2w      = (const float*)d_in[4];
    const float* W2b      = (const float*)d_in[5];
    const float* Vw       = (const float*)d_in[6];
    // d_in[7] = V_b: uniform shift across the seq axis -> softmax-invariant; skipped.

    float* out = (float*)d_out;
    float* ctx = out;            // [64*1024] context_vector
    float* att = out + 65536;    // [64*1024] logits -> attention weights (in place)

    short* Bws = (short*)d_ws;                                   // 2 MB packed W1
    float* hb  = (float*)((char*)d_ws + (size_t)2*1024*1024);    // 256 KB

    hipMemsetAsync(d_out, 0, (size_t)131072 * sizeof(float), stream);  // ctx + logits zero
    pack_w1<<<512, 256, 0, stream>>>(W1w, Bws);
    hb_kernel<<<dim3(4, 64), 256, 0, stream>>>(hidden, W2w, W2b, W1b, hb);
    gemm_score<<<4096, 256, 0, stream>>>(features, Bws, hb, Vw, att);
    softmax_seq<<<64, 256, 0, stream>>>(att);
    context_kernel<<<dim3(4, 4, 64), 256, 0, stream>>>(features, att, ctx);
}